// Round 1
// baseline (364.327 us; speedup 1.0000x reference)
//
#include <hip/hip_runtime.h>
#include <stdint.h>

#define BT      128
#define NPATCH  256
#define DV      1024
#define NB      4
#define NHEADS  4
#define HD      64
#define DB      256
#define NH16    16
#define SCALE   0.125f
#define LNEPS   1e-5f

// ---- ws layout (float element offsets) ----
#define OFF_GWQ    0u          // 16*1024 fp32  (g-folded wq)
#define OFF_BWS    16384u      // 16384 u16 bf16 B-frags = 8192 floats
#define OFF_S      24576u      // 16: S_nh = sum_i g_i*wq_i
#define OFF_CB     24592u      // 16: Cb_nh = sum_i b_i*wq_i + bk.q
#define OFF_DRAW   24608u      // 32768*16 raw dots
#define OFF_STATS  548896u     // 32768*{mu,rstd}
#define OFF_ATTN   614432u     // 128*16*256
#define OFF_DIV    1138720u    // 128*6
#define OFF_XBAR   1139488u    // 2*128*16*1024
// total 5,333,792 floats ~= 20.4 MiB

typedef short bf16x8 __attribute__((ext_vector_type(8)));
typedef float f32x4  __attribute__((ext_vector_type(4)));

__device__ __forceinline__ short f2bf(float f) {
    union { float f; unsigned u; } v; v.f = f;
    unsigned u = v.u;
    unsigned r = (u + 0x7fffu + ((u >> 16) & 1u)) >> 16;  // RNE
    return (short)r;
}

// ---- P: wq[nh,i] = sum_d Wk[n,i,h*64+d]*q[n,h,d]; fold gamma; S, Cb ----
__global__ __launch_bounds__(256) void kP(const float* __restrict__ Wk,
                                          const float* __restrict__ bk,
                                          const float* __restrict__ q,
                                          const float* __restrict__ g,
                                          const float* __restrict__ b,
                                          float* __restrict__ ws) {
    const int nh = blockIdx.x;          // 0..15 = n*4+h
    const int n = nh >> 2, h = nh & 3;
    __shared__ float qs[HD];
    __shared__ float redS[256], redC[256];
    const int t = threadIdx.x;
    if (t < HD) qs[t] = q[nh * HD + t];
    __syncthreads();
    float pS = 0.f, pC = 0.f;
    for (int it = 0; it < 4; ++it) {
        const int i = it * 256 + t;
        const float* wrow = Wk + ((size_t)n * DV + i) * DB + h * HD;
        float acc = 0.f;
        #pragma unroll
        for (int d = 0; d < HD; d += 4) {
            float4 wv = *(const float4*)(wrow + d);
            acc += wv.x * qs[d] + wv.y * qs[d + 1] + wv.z * qs[d + 2] + wv.w * qs[d + 3];
        }
        float gw = g[i] * acc;
        ws[OFF_GWQ + nh * DV + i] = gw;
        pS += gw;
        pC += b[i] * acc;
    }
    redS[t] = pS; redC[t] = pC;
    __syncthreads();
    for (int s = 128; s > 0; s >>= 1) {
        if (t < s) { redS[t] += redS[t + s]; redC[t] += redC[t + s]; }
        __syncthreads();
    }
    if (t == 0) {
        float bkq = 0.f;
        for (int d = 0; d < HD; ++d) bkq += bk[n * DB + h * HD + d] * qs[d];
        ws[OFF_S + nh]  = redS[0];
        ws[OFF_CB + nh] = redC[0] + bkq;
    }
}

// ---- P2: pack gwq into MFMA B-operand layout, bf16 ----
// B[k][nh] for 16x16x32: lane l holds B[kt*32 + (l>>4)*8 + j][l&15], j=0..7
__global__ __launch_bounds__(1024) void kP2(float* __restrict__ ws) {
    unsigned short* bws = (unsigned short*)(ws + OFF_BWS);
    const float* gwq = ws + OFF_GWQ;
    const int t = threadIdx.x;
    for (int it = 0; it < 16; ++it) {
        const int idx  = it * 1024 + t;       // 0..16383 = (kt*64+lane)*8+j
        const int j    = idx & 7;
        const int lane = (idx >> 3) & 63;
        const int kt   = idx >> 9;
        const int nh   = lane & 15;
        const int k    = kt * 32 + ((lane >> 4) * 8) + j;
        bws[idx] = (unsigned short)f2bf(gwq[nh * DV + k]);
    }
}

// ---- A: raw dots D[row][nh] via MFMA + LN stats (sum/sumsq) ----
__global__ __launch_bounds__(256) void kA(const float* __restrict__ x,
                                          float* __restrict__ ws) {
    const int t = threadIdx.x;
    const int wave = t >> 6, lane = t & 63;
    const int tile = blockIdx.x * 4 + wave;   // 0..2047, 16 rows each
    const int m = lane & 15, oct = lane >> 4;
    const int row0 = tile * 16;
    const float* xrow = x + (size_t)(row0 + m) * DV + oct * 8;
    const bf16x8* bfp = (const bf16x8*)((const unsigned short*)(ws + OFF_BWS));

    f32x4 acc = {0.f, 0.f, 0.f, 0.f};
    float sum = 0.f, sq = 0.f;
    #pragma unroll 4
    for (int kt = 0; kt < 32; ++kt) {
        float4 a0 = *(const float4*)(xrow + kt * 32);
        float4 a1 = *(const float4*)(xrow + kt * 32 + 4);
        bf16x8 af;
        af[0] = f2bf(a0.x); af[1] = f2bf(a0.y); af[2] = f2bf(a0.z); af[3] = f2bf(a0.w);
        af[4] = f2bf(a1.x); af[5] = f2bf(a1.y); af[6] = f2bf(a1.z); af[7] = f2bf(a1.w);
        bf16x8 bfr = bfp[kt * 64 + lane];
        acc = __builtin_amdgcn_mfma_f32_16x16x32_bf16(af, bfr, acc, 0, 0, 0);
        sum += a0.x + a0.y + a0.z + a0.w + a1.x + a1.y + a1.z + a1.w;
        sq  += a0.x * a0.x + a0.y * a0.y + a0.z * a0.z + a0.w * a0.w
             + a1.x * a1.x + a1.y * a1.y + a1.z * a1.z + a1.w * a1.w;
    }
    // combine the 4 k-octet partials of each row m
    sum += __shfl_xor(sum, 16); sum += __shfl_xor(sum, 32);
    sq  += __shfl_xor(sq, 16);  sq  += __shfl_xor(sq, 32);
    if (lane < 16) {
        float mu   = sum * (1.f / 1024.f);
        float var  = sq * (1.f / 1024.f) - mu * mu;
        float rstd = rsqrtf(var + LNEPS);
        ws[OFF_STATS + (size_t)(row0 + lane) * 2 + 0] = mu;
        ws[OFF_STATS + (size_t)(row0 + lane) * 2 + 1] = rstd;
    }
    // C-layout: col=lane&15 (nh), row=(lane>>4)*4+r
    #pragma unroll
    for (int r = 0; r < 4; ++r)
        ws[OFF_DRAW + (size_t)(row0 + oct * 4 + r) * 16 + m] = acc[r];
}

// ---- B: scores -> softmax -> attn (ws) + diversity partials ----
__global__ __launch_bounds__(256) void kB(float* __restrict__ ws) {
    const int bt = blockIdx.x;
    const int t = threadIdx.x;            // t = patch p in phase 1
    __shared__ float s_s[NH16 * NPATCH];  // scores then attn, 16KB
    __shared__ float aavg[NB * NPATCH];
    __shared__ float Ss[NH16], Cbs[NH16];
    if (t < NH16) Ss[t] = ws[OFF_S + t];
    else if (t < 32) Cbs[t - 16] = ws[OFF_CB + (t - 16)];
    const float mu   = ws[OFF_STATS + (size_t)(bt * NPATCH + t) * 2 + 0];
    const float rstd = ws[OFF_STATS + (size_t)(bt * NPATCH + t) * 2 + 1];
    __syncthreads();
    const float* dr = ws + OFF_DRAW + (size_t)(bt * NPATCH + t) * 16;
    #pragma unroll
    for (int nh = 0; nh < NH16; ++nh) {
        float D = dr[nh];
        s_s[nh * NPATCH + t] = (rstd * (D - mu * Ss[nh]) + Cbs[nh]) * SCALE;
    }
    __syncthreads();
    const int wave = t >> 6, lane = t & 63;
    for (int r = 0; r < 4; ++r) {
        const int nh = wave * 4 + r;
        float4 v = *(float4*)&s_s[nh * NPATCH + lane * 4];
        float mx = fmaxf(fmaxf(v.x, v.y), fmaxf(v.z, v.w));
        for (int d = 1; d < 64; d <<= 1) mx = fmaxf(mx, __shfl_xor(mx, d));
        float e0 = __expf(v.x - mx), e1 = __expf(v.y - mx);
        float e2 = __expf(v.z - mx), e3 = __expf(v.w - mx);
        float s = e0 + e1 + e2 + e3;
        for (int d = 1; d < 64; d <<= 1) s += __shfl_xor(s, d);
        float inv = 1.f / s;
        float4 a; a.x = e0 * inv; a.y = e1 * inv; a.z = e2 * inv; a.w = e3 * inv;
        *(float4*)&s_s[nh * NPATCH + lane * 4] = a;
        *(float4*)(ws + OFF_ATTN + (size_t)(bt * NH16 + nh) * NPATCH + lane * 4) = a;
    }
    __syncthreads();
    #pragma unroll
    for (int n = 0; n < NB; ++n)
        aavg[n * NPATCH + t] = 0.25f * (s_s[(n * 4 + 0) * NPATCH + t] + s_s[(n * 4 + 1) * NPATCH + t]
                                      + s_s[(n * 4 + 2) * NPATCH + t] + s_s[(n * 4 + 3) * NPATCH + t]);
    __syncthreads();
    if (wave == 0) {
        float nrm[NB];
        #pragma unroll
        for (int n = 0; n < NB; ++n) {
            float4 v = *(float4*)&aavg[n * NPATCH + lane * 4];
            float ss = v.x * v.x + v.y * v.y + v.z * v.z + v.w * v.w;
            for (int d = 1; d < 64; d <<= 1) ss += __shfl_xor(ss, d);
            nrm[n] = fmaxf(sqrtf(ss), 1e-8f);
        }
        int pi = 0;
        for (int i = 0; i < NB; ++i)
            for (int j = i + 1; j < NB; ++j) {
                float4 va = *(float4*)&aavg[i * NPATCH + lane * 4];
                float4 vb = *(float4*)&aavg[j * NPATCH + lane * 4];
                float dd = va.x * vb.x + va.y * vb.y + va.z * vb.z + va.w * vb.w;
                for (int d = 1; d < 64; d <<= 1) dd += __shfl_xor(dd, d);
                if (lane == 0) ws[OFF_DIV + bt * 6 + pi] = dd / (nrm[i] * nrm[j]);
                ++pi;
            }
    }
}

// ---- C: xbar[nh, :] = sum_p attn[nh,p] * LN(x[bt,p,:])   (thread-per-dim) ----
__global__ __launch_bounds__(1024) void kC(const float* __restrict__ x,
                                           const float* __restrict__ g,
                                           const float* __restrict__ b,
                                           float* __restrict__ ws) {
    const int bt = blockIdx.x;
    const int half = blockIdx.y;           // p-split for occupancy
    const int t = threadIdx.x;             // dim 0..1023
    __shared__ float att_s[128 * 16];      // [p'][nh]
    __shared__ float st_s[128 * 2];        // mu,rstd
    for (int idx = t; idx < 2048; idx += 1024) {
        int p = idx >> 4, nh = idx & 15;
        att_s[p * 16 + nh] = ws[OFF_ATTN + (size_t)(bt * NH16 + nh) * NPATCH + half * 128 + p];
    }
    if (t < 256) st_s[t] = ws[OFF_STATS + (size_t)(bt * NPATCH + half * 128) * 2 + t];
    const float gt = g[t], bb = b[t];
    float acc[16];
    #pragma unroll
    for (int i = 0; i < 16; ++i) acc[i] = 0.f;
    __syncthreads();
    const float* xp = x + (size_t)(bt * NPATCH + half * 128) * DV + t;
    for (int p = 0; p < 128; ++p) {
        float xv = xp[(size_t)p * DV];
        float y = (xv - st_s[p * 2]) * st_s[p * 2 + 1] * gt + bb;
        float4 a0 = *(const float4*)&att_s[p * 16 + 0];
        float4 a1 = *(const float4*)&att_s[p * 16 + 4];
        float4 a2 = *(const float4*)&att_s[p * 16 + 8];
        float4 a3 = *(const float4*)&att_s[p * 16 + 12];
        acc[0]  += a0.x * y; acc[1]  += a0.y * y; acc[2]  += a0.z * y; acc[3]  += a0.w * y;
        acc[4]  += a1.x * y; acc[5]  += a1.y * y; acc[6]  += a1.z * y; acc[7]  += a1.w * y;
        acc[8]  += a2.x * y; acc[9]  += a2.y * y; acc[10] += a2.z * y; acc[11] += a2.w * y;
        acc[12] += a3.x * y; acc[13] += a3.y * y; acc[14] += a3.z * y; acc[15] += a3.w * y;
    }
    #pragma unroll
    for (int nh = 0; nh < 16; ++nh)
        ws[OFF_XBAR + ((size_t)(half * BT + bt) * 16 + nh) * DV + t] = acc[nh];
}

// ---- D: pooled = xbar @ Wv_slice + bv ; out = pooled @ Wo + bo -> streams ----
__global__ __launch_bounds__(256) void kD(const float* __restrict__ Wv,
                                          const float* __restrict__ bv,
                                          const float* __restrict__ Wo,
                                          const float* __restrict__ bo,
                                          const float* __restrict__ ws,
                                          float* __restrict__ out) {
    const int n = blockIdx.x & 3;
    const int bt0 = (blockIdx.x >> 2) * 4;   // 4 bt per block
    const int t = threadIdx.x;               // output channel c (phase1) / j (phase2)
    __shared__ float xs[4 * DV * 4];         // [h][i][bt] 64 KB
    __shared__ float ps[DB * 4];             // [c][bt]
    for (int idx = t; idx < 16384; idx += 256) {
        int btl = idx >> 12;
        int h = (idx >> 10) & 3;
        int i = idx & 1023;
        size_t b0 = OFF_XBAR + ((size_t)(bt0 + btl) * 16 + (n * 4 + h)) * DV + i;
        size_t b1 = OFF_XBAR + ((size_t)(BT + bt0 + btl) * 16 + (n * 4 + h)) * DV + i;
        xs[(h * DV + i) * 4 + btl] = ws[b0] + ws[b1];
    }
    __syncthreads();
    const int h = t >> 6;
    float p0, p1, p2, p3;
    p0 = p1 = p2 = p3 = bv[n * DB + t];
    const float* wv = Wv + (size_t)n * DV * DB + t;
    for (int i = 0; i < DV; ++i) {
        float w = wv[(size_t)i * DB];
        float4 xb = *(const float4*)&xs[(h * DV + i) * 4];
        p0 += xb.x * w; p1 += xb.y * w; p2 += xb.z * w; p3 += xb.w * w;
    }
    ps[t * 4 + 0] = p0; ps[t * 4 + 1] = p1; ps[t * 4 + 2] = p2; ps[t * 4 + 3] = p3;
    __syncthreads();
    float o0, o1, o2, o3;
    o0 = o1 = o2 = o3 = bo[n * DB + t];
    const float* wo = Wo + (size_t)n * DB * DB + t;
    for (int c = 0; c < DB; ++c) {
        float w = wo[(size_t)c * DB];
        float4 pv = *(const float4*)&ps[c * 4];
        o0 += pv.x * w; o1 += pv.y * w; o2 += pv.z * w; o3 += pv.w * w;
    }
    out[((size_t)(bt0 + 0) * 4 + n) * DB + t] = o0;
    out[((size_t)(bt0 + 1) * 4 + n) * DB + t] = o1;
    out[((size_t)(bt0 + 2) * 4 + n) * DB + t] = o2;
    out[((size_t)(bt0 + 3) * 4 + n) * DB + t] = o3;
}

// ---- E: finalize diversity loss ----
__global__ __launch_bounds__(256) void kE(const float* __restrict__ ws,
                                          float* __restrict__ out) {
    const int t = threadIdx.x;
    float acc = 0.f;
    for (int idx = t; idx < 768; idx += 256) acc += ws[OFF_DIV + idx];
    __shared__ float red[4];
    for (int d = 1; d < 64; d <<= 1) acc += __shfl_xor(acc, d);
    if ((t & 63) == 0) red[t >> 6] = acc;
    __syncthreads();
    if (t == 0) {
        float tot = red[0] + red[1] + red[2] + red[3];
        out[131072] = 0.1f * tot / (6.f * 128.f);
    }
}

extern "C" void kernel_launch(void* const* d_in, const int* in_sizes, int n_in,
                              void* d_out, int out_size, void* d_ws, size_t ws_size,
                              hipStream_t stream) {
    const float* x  = (const float*)d_in[0];
    const float* g  = (const float*)d_in[1];
    const float* b  = (const float*)d_in[2];
    const float* q  = (const float*)d_in[3];
    const float* Wk = (const float*)d_in[4];
    const float* bk = (const float*)d_in[5];
    const float* Wv = (const float*)d_in[6];
    const float* bv = (const float*)d_in[7];
    const float* Wo = (const float*)d_in[8];
    const float* bo = (const float*)d_in[9];
    float* out = (float*)d_out;
    float* ws  = (float*)d_ws;

    hipLaunchKernelGGL(kP,  dim3(16),     dim3(256),  0, stream, Wk, bk, q, g, b, ws);
    hipLaunchKernelGGL(kP2, dim3(1),      dim3(1024), 0, stream, ws);
    hipLaunchKernelGGL(kA,  dim3(512),    dim3(256),  0, stream, x, ws);
    hipLaunchKernelGGL(kB,  dim3(128),    dim3(256),  0, stream, ws);
    hipLaunchKernelGGL(kC,  dim3(128, 2), dim3(1024), 0, stream, x, g, b, ws);
    hipLaunchKernelGGL(kD,  dim3(128),    dim3(256),  0, stream, Wv, bv, Wo, bo, ws, out);
    hipLaunchKernelGGL(kE,  dim3(1),      dim3(256),  0, stream, ws, out);
}